// Round 5
// baseline (980.900 us; speedup 1.0000x reference)
//
#include <hip/hip_runtime.h>

// VariationalMPS: <M|H|M> / <M|M> via split-half environment sweeps.
// R5: persistent kernel, NO cache-maintenance barriers. All cross-block
// intermediates (envs, T2, Tn, Mrev/Hrev, partials) use volatile (sc0 sc1)
// accesses -> coherent at the memory-side Infinity Cache; barriers are
// relaxed agent-scope RMW + relaxed volatile polls, zero fences. Inputs and
// Mrev/Hrev stay hot in L2/L1 across all 20 steps.

#define D 128
#define W 8
#define NS 40
#define HALF 20
#define MSZ (D * 2 * D)      // 32768
#define HSZ (W * W * 2 * 2)  // 256
#define LSZ (D * W * D)      // 131072
#define NSZ (D * D)          // 16384
#define T2SZ (D * W * D * 2) // 262144
#define TNSZ (D * 2 * D)     // 32768

#define OFF_LL 0
#define OFF_LR (OFF_LL + LSZ)
#define OFF_NL (OFF_LR + LSZ)
#define OFF_NR (OFF_NL + NSZ)
#define OFF_T2L (OFF_NR + NSZ)
#define OFF_T2R (OFF_T2L + T2SZ)
#define OFF_TNL (OFF_T2R + T2SZ)
#define OFF_TNR (OFF_TNL + TNSZ)
#define OFF_MREV (OFF_TNR + TNSZ)
#define OFF_HREV (OFF_MREV + HALF * MSZ)
#define OFF_PART (OFF_HREV + HALF * HSZ)
#define OFF_PARTN (OFF_PART + 128)
#define OFF_BAR (OFF_PARTN + 128)

#define NBLK 192
#define NLEAF 8
#define LEAF_STRIDE 16
#define SLOT_U32 (NLEAF * LEAF_STRIDE)
#define SLOTS 44
#define REGION_U32 (SLOTS * SLOT_U32)
#define NREGION 5
#define BAR_TOTAL_U32 (NREGION * REGION_U32)

__global__ __launch_bounds__(256) void k_zero(float* ws) {
    unsigned* bar = (unsigned*)(ws + OFF_BAR);
    int idx = blockIdx.x * 256 + threadIdx.x;
    if (idx < BAR_TOTAL_U32) bar[idx] = 0u;
}

// Barrier with NO cache maintenance. Entry __syncthreads drains each wave's
// vmcnt (volatile stores are then visible at fabric). Arrival: relaxed
// agent-scope RMW spread over 8 leaf lines. Wait: 8 lanes poll one leaf each
// with volatile (sc0 sc1) loads. Exit __syncthreads. Consumers read shared
// data with volatile loads, so no acquire invalidate is needed.
__device__ __forceinline__ void bar_sync(unsigned* region, int slot, int leaf,
                                         int expect_per_leaf) {
    unsigned* s = region + slot * SLOT_U32;
    __syncthreads();
    __builtin_amdgcn_s_waitcnt(0x0F70); // vmcnt(0); exp/lgkm unconstrained
    if (threadIdx.x == 0) {
        __hip_atomic_fetch_add(s + leaf * LEAF_STRIDE, 1u, __ATOMIC_RELAXED,
                               __HIP_MEMORY_SCOPE_AGENT);
    }
    if (threadIdx.x < NLEAF) {
        volatile unsigned* c = s + threadIdx.x * LEAF_STRIDE;
        while ((int)*c < expect_per_leaf) __builtin_amdgcn_s_sleep(8);
    }
    __syncthreads();
}

__global__ __launch_bounds__(256) void k_sweep(const float* __restrict__ Min,
                                               const float* __restrict__ Hin,
                                               float* __restrict__ ws,
                                               float* __restrict__ out) {
    __shared__ float sm[7680];
    unsigned* bar = (unsigned*)(ws + OFF_BAR);
    volatile float* vws = (volatile float*)ws;
    const int bid = blockIdx.x;
    const int t = threadIdx.x;

    int chain, lid, cexp;
    if (bid < 64)       { chain = 0; lid = bid;       cexp = 8; }
    else if (bid < 128) { chain = 1; lid = bid - 64;  cexp = 8; }
    else if (bid < 160) { chain = 2; lid = bid - 128; cexp = 4; }
    else                { chain = 3; lid = bid - 160; cexp = 4; }
    const int side = (chain == 1 || chain == 3);
    const int leaf = lid & (NLEAF - 1);
    unsigned* creg = bar + chain * REGION_U32;
    unsigned* greg = bar + 4 * REGION_U32;
    const int gleaf = bid & (NLEAF - 1);

    // ---- init envs + reversed tensors (volatile stores -> fabric) ----
    for (int idx = bid * 256 + t; idx < OFF_T2L; idx += NBLK * 256) {
        float v = 0.f;
        if (idx == 0) v = 1.f;
        else if (idx == OFF_LR + (W - 1) * D) v = 1.f;
        else if (idx == OFF_NL) v = 1.f;
        else if (idx == OFF_NR) v = 1.f;
        vws[idx] = v;
    }
    for (int idx = bid * 256 + t; idx < HALF * MSZ; idx += NBLK * 256) {
        int k = idx >> 15;
        int r = idx & (MSZ - 1);
        int p = r >> 8;
        int i = (r >> 7) & 1;
        int a = r & 127;
        vws[OFF_MREV + idx] = Min[(NS - 1 - k) * MSZ + a * 256 + i * 128 + p];
    }
    for (int idx = bid * 256 + t; idx < HALF * HSZ; idx += NBLK * 256) {
        int k = idx >> 8;
        int r = idx & 255;
        int x = r >> 5, w = (r >> 2) & 7, i = (r >> 1) & 1, j = r & 1;
        vws[OFF_HREV + idx] = Hin[(NS - 1 - k) * HSZ + w * 32 + x * 4 + i * 2 + j];
    }
    bar_sync(greg, 0, gleaf, NBLK / NLEAF);

    // ---- sweep ----
    for (int k = 0; k < HALF; ++k) {
        // m / h are immutable after the init barrier -> plain cached reads
        const float* m = side ? (ws + OFF_MREV + k * MSZ) : (Min + k * MSZ);
        // ===== phase A =====
        if (chain < 2) {
            int b0 = (lid & 7) * 16;
            int p0 = (lid >> 3) * 16;
            const volatile float* Lsrc = vws + (side ? OFF_LR : OFF_LL);
            const float* h = side ? (ws + OFF_HREV + k * HSZ) : (Hin + k * HSZ);
            volatile float* T2 = vws + (side ? OFF_T2R : OFF_T2L);
            float* Ls = sm;          // [32a][16b][8w pad->12], row stride 200
            float* ms = sm + 6400;   // [32a][2i][16p]
            float* hs = sm + 7424;   // [16wi][16xj]
            hs[t] = h[((t >> 4) >> 1) * 32 + ((t & 15) >> 1) * 4 +
                      ((t >> 4) & 1) * 2 + (t & 1)];
            int b_l = t & 15, p_l = t >> 4;
            float acc[8][2];
#pragma unroll
            for (int w = 0; w < 8; ++w) { acc[w][0] = 0.f; acc[w][1] = 0.f; }
            for (int c = 0; c < 4; ++c) {
                int a0 = c * 32;
                __syncthreads();
#pragma unroll
                for (int u = 0; u < 4; ++u) {
                    int e = u * 256 + t;
                    int aa = e >> 5, w = (e >> 2) & 7, bq = e & 3;
                    const volatile float* src =
                        &Lsrc[(a0 + aa) * 1024 + w * 128 + b0 + bq * 4];
                    float v0 = src[0], v1 = src[1], v2 = src[2], v3 = src[3];
                    float* dst = &Ls[aa * 200 + bq * 48 + w];
                    dst[0] = v0; dst[12] = v1; dst[24] = v2; dst[36] = v3;
                }
                {
                    int aa = t >> 3, i = (t >> 2) & 1, pq = t & 3;
                    const float4 v = *(const float4*)&m[(a0 + aa) * 256 + i * 128 + p0 + pq * 4];
                    *(float4*)&ms[aa * 32 + i * 16 + pq * 4] = v;
                }
                __syncthreads();
#pragma unroll 4
                for (int aa = 0; aa < 32; ++aa) {
                    float4 l0 = *(float4*)&Ls[aa * 200 + b_l * 12];
                    float4 l1 = *(float4*)&Ls[aa * 200 + b_l * 12 + 4];
                    float m0 = ms[aa * 32 + p_l];
                    float m1 = ms[aa * 32 + 16 + p_l];
                    acc[0][0] += l0.x * m0; acc[0][1] += l0.x * m1;
                    acc[1][0] += l0.y * m0; acc[1][1] += l0.y * m1;
                    acc[2][0] += l0.z * m0; acc[2][1] += l0.z * m1;
                    acc[3][0] += l0.w * m0; acc[3][1] += l0.w * m1;
                    acc[4][0] += l1.x * m0; acc[4][1] += l1.x * m1;
                    acc[5][0] += l1.y * m0; acc[5][1] += l1.y * m1;
                    acc[6][0] += l1.z * m0; acc[6][1] += l1.z * m1;
                    acc[7][0] += l1.w * m0; acc[7][1] += l1.w * m1;
                }
            }
            float o[16];
#pragma unroll
            for (int xj = 0; xj < 16; ++xj) o[xj] = 0.f;
#pragma unroll
            for (int wi = 0; wi < 16; ++wi) {
                float tv = acc[wi >> 1][wi & 1];
                float4 h0 = *(float4*)&hs[wi * 16];
                float4 h1 = *(float4*)&hs[wi * 16 + 4];
                float4 h2 = *(float4*)&hs[wi * 16 + 8];
                float4 h3 = *(float4*)&hs[wi * 16 + 12];
                o[0] += tv * h0.x;  o[1] += tv * h0.y;  o[2] += tv * h0.z;  o[3] += tv * h0.w;
                o[4] += tv * h1.x;  o[5] += tv * h1.y;  o[6] += tv * h1.z;  o[7] += tv * h1.w;
                o[8] += tv * h2.x;  o[9] += tv * h2.y;  o[10] += tv * h2.z; o[11] += tv * h2.w;
                o[12] += tv * h3.x; o[13] += tv * h3.y; o[14] += tv * h3.z; o[15] += tv * h3.w;
            }
            int b = b0 + b_l, p = p0 + p_l;
            int base = p * 2048 + b * 2; // T2[p][x][b][j]
#pragma unroll
            for (int x = 0; x < 8; ++x) {
                T2[base + x * 256] = o[x * 2];
                T2[base + x * 256 + 1] = o[x * 2 + 1];
            }
        } else {
            int b0 = (lid & 3) * 32;
            int c0 = (lid >> 2) * 32;
            const volatile float* Nsrc = vws + (side ? OFF_NR : OFF_NL);
            volatile float* Tn = vws + (side ? OFF_TNR : OFF_TNL);
            float* As = sm;         // [32][33]
            float* Bs = sm + 1056;  // [32][33]
            int ty = t >> 4, tx = t & 15;
            float a00 = 0, a01 = 0, a10 = 0, a11 = 0;
            for (int c = 0; c < 4; ++c) {
                int a0 = c * 32;
                __syncthreads();
                for (int u = 0; u < 4; ++u) {
                    int e = u * 256 + t;
                    int kk = e >> 5, col = e & 31;
                    As[kk * 33 + col] = Nsrc[(a0 + kk) * 128 + b0 + col];
                    Bs[kk * 33 + col] = m[(a0 + kk) * 256 + c0 + col];
                }
                __syncthreads();
                for (int kk = 0; kk < 32; ++kk) {
                    float av0 = As[kk * 33 + 2 * ty], av1 = As[kk * 33 + 2 * ty + 1];
                    float bv0 = Bs[kk * 33 + 2 * tx], bv1 = Bs[kk * 33 + 2 * tx + 1];
                    a00 += av0 * bv0;
                    a01 += av0 * bv1;
                    a10 += av1 * bv0;
                    a11 += av1 * bv1;
                }
            }
            int b_ = b0 + 2 * ty;
            int ip0 = c0 + 2 * tx, ip1 = ip0 + 1;
            int p0_ = ip0 & 127, i0 = ip0 >> 7;
            int p1_ = ip1 & 127, i1 = ip1 >> 7;
            Tn[p0_ * 256 + b_ * 2 + i0] = a00;
            Tn[p1_ * 256 + b_ * 2 + i1] = a01;
            Tn[p0_ * 256 + (b_ + 1) * 2 + i0] = a10;
            Tn[p1_ * 256 + (b_ + 1) * 2 + i1] = a11;
        }
        bar_sync(creg, 2 * k, leaf, cexp);

        // ===== phase B =====
        if (chain < 2) {
            // energy: C=L' (1024x128) = T2 (1024x256) x m (256x128); 32x64 tile
            int r0 = (lid & 31) * 32;
            int c0 = (lid >> 5) * 64;
            const volatile float* A = vws + (side ? OFF_T2R : OFF_T2L);
            volatile float* C = vws + (side ? OFF_LR : OFF_LL);
            float* As = sm;         // [32k][32r pad->34]
            float* Bs = sm + 1088;  // [32k][64c pad->68]
            int ty = t >> 4, tx = t & 15;
            float a00 = 0, a01 = 0, a02 = 0, a03 = 0;
            float a10 = 0, a11 = 0, a12 = 0, a13 = 0;
            for (int c = 0; c < 8; ++c) {
                int k0 = c * 32;
                __syncthreads();
                {
                    int rr = t >> 3, kq = t & 7;
                    const volatile float* src = &A[(r0 + rr) * 256 + k0 + kq * 4];
                    float v0 = src[0], v1 = src[1], v2 = src[2], v3 = src[3];
                    float* dst = &As[kq * 136 + rr];
                    dst[0] = v0; dst[34] = v1; dst[68] = v2; dst[102] = v3;
                }
#pragma unroll
                for (int u = 0; u < 2; ++u) {
                    int e = u * 256 + t;
                    int kk = e >> 4, cq = e & 15;
                    const float4 v = *(const float4*)&m[(k0 + kk) * 128 + c0 + cq * 4];
                    *(float4*)&Bs[kk * 68 + cq * 4] = v;
                }
                __syncthreads();
#pragma unroll 8
                for (int kk = 0; kk < 32; ++kk) {
                    float2 av = *(float2*)&As[kk * 34 + 2 * ty];
                    float4 bv = *(float4*)&Bs[kk * 68 + 4 * tx];
                    a00 += av.x * bv.x; a01 += av.x * bv.y; a02 += av.x * bv.z; a03 += av.x * bv.w;
                    a10 += av.y * bv.x; a11 += av.y * bv.y; a12 += av.y * bv.z; a13 += av.y * bv.w;
                }
            }
            int r = r0 + 2 * ty, cc = c0 + 4 * tx;
            C[r * 128 + cc]     = a00;
            C[r * 128 + cc + 1] = a01;
            C[r * 128 + cc + 2] = a02;
            C[r * 128 + cc + 3] = a03;
            C[(r + 1) * 128 + cc]     = a10;
            C[(r + 1) * 128 + cc + 1] = a11;
            C[(r + 1) * 128 + cc + 2] = a12;
            C[(r + 1) * 128 + cc + 3] = a13;
        } else {
            // norm: C=N' (128x128) = Tn (128x256) x m (256x128); 16x32 tile
            int r0 = (lid & 7) * 16;
            int c0 = (lid >> 3) * 32;
            const volatile float* A = vws + (side ? OFF_TNR : OFF_TNL);
            volatile float* C = vws + (side ? OFF_NR : OFF_NL);
            float* As = sm;         // [32k][16r pad->17]
            float* Bs = sm + 544;   // [32k][32c pad->34]
            int ty = t >> 4, tx = t & 15;
            float a0 = 0, a1 = 0;
            for (int c = 0; c < 8; ++c) {
                int k0 = c * 32;
                __syncthreads();
                if (t < 128) {
                    int rr = t >> 3, kq = t & 7;
                    const volatile float* src = &A[(r0 + rr) * 256 + k0 + kq * 4];
                    float v0 = src[0], v1 = src[1], v2 = src[2], v3 = src[3];
                    float* dst = &As[kq * 68 + rr];
                    dst[0] = v0; dst[17] = v1; dst[34] = v2; dst[51] = v3;
                }
                {
                    int kk = t >> 3, cq = t & 7;
                    const float4 v = *(const float4*)&m[(k0 + kk) * 128 + c0 + cq * 4];
                    *(float4*)&Bs[kk * 34 + cq * 4] = v;
                }
                __syncthreads();
                for (int kk = 0; kk < 32; ++kk) {
                    float av = As[kk * 17 + ty];
                    float2 bv = *(float2*)&Bs[kk * 34 + 2 * tx];
                    a0 += av * bv.x;
                    a1 += av * bv.y;
                }
            }
            C[(r0 + ty) * 128 + c0 + 2 * tx]     = a0;
            C[(r0 + ty) * 128 + c0 + 2 * tx + 1] = a1;
        }
        bar_sync(creg, 2 * k + 1, leaf, cexp);
    }

    bar_sync(greg, 1, gleaf, NBLK / NLEAF);

    // ---- dot partials: blocks 0..127 ----
    if (bid < 128) {
        float* se = sm;
        float* sn = sm + 256;
        const volatile float* LL = vws + OFF_LL;
        const volatile float* LR = vws + OFF_LR;
        float e = 0.f;
#pragma unroll
        for (int u = 0; u < 4; ++u) {
            int i = bid * 1024 + u * 256 + t;
            e += LL[i] * LR[i];
        }
        float n = 0.f;
        if (t < 128) {
            int i = bid * 128 + t;
            n = vws[OFF_NL + i] * vws[OFF_NR + i];
        }
        se[t] = e;
        sn[t] = n;
        __syncthreads();
        for (int s = 128; s > 0; s >>= 1) {
            if (t < s) { se[t] += se[t + s]; sn[t] += sn[t + s]; }
            __syncthreads();
        }
        if (t == 0) {
            vws[OFF_PART + bid] = se[0];
            vws[OFF_PARTN + bid] = sn[0];
        }
    }
    bar_sync(greg, 2, gleaf, NBLK / NLEAF);

    // ---- final reduce + loss ----
    if (bid == 0) {
        float* se = sm;
        float* sn = sm + 128;
        if (t < 128) {
            se[t] = vws[OFF_PART + t];
            sn[t] = vws[OFF_PARTN + t];
        }
        __syncthreads();
        for (int s = 64; s > 0; s >>= 1) {
            if (t < s) { se[t] += se[t + s]; sn[t] += sn[t + s]; }
            __syncthreads();
        }
        if (t == 0) {
            float E = se[0], Nm = sn[0];
            out[0] = E;
            out[1] = Nm;
            out[2] = E / Nm;
            out[3] = fmaxf(Nm - 10000.0f, 0.0f);
        }
    }
}

extern "C" void kernel_launch(void* const* d_in, const int* in_sizes, int n_in,
                              void* d_out, int out_size, void* d_ws, size_t ws_size,
                              hipStream_t stream) {
    const float* Min = (const float*)d_in[0];
    const float* Hin = (const float*)d_in[1];
    float* ws = (float*)d_ws;
    float* out = (float*)d_out;
    (void)in_sizes; (void)n_in; (void)out_size; (void)ws_size;

    k_zero<<<dim3((BAR_TOTAL_U32 + 255) / 256), dim3(256), 0, stream>>>(ws);
    k_sweep<<<dim3(NBLK), dim3(256), 0, stream>>>(Min, Hin, ws, out);
}

// Round 6
// 588.602 us; speedup vs baseline: 1.6665x; 1.6665x over previous
//
#include <hip/hip_runtime.h>

// VariationalMPS: <M|H|M> / <M|M> via split-half environment sweeps.
// R6: back to multi-kernel (kernel boundary = cheap coherence), but ONE fused
// kernel per site: the contraction chain is parallel in p, so each block owns
// a p-slice and carries T1/T2 through LDS (no T2 global round-trip, no
// intra-step cross-block deps). L/N double-buffered across steps.
// 23 dispatches total (vs 44 in R2).

#define D 128
#define W 8
#define NS 40
#define HALF 20
#define MSZ 32768   // floats per site M (128*2*128)
#define HSZ 256     // floats per site H
#define LSZ 131072  // energy env (128*8*128)
#define NSZ 16384   // norm env (128*128)

// workspace float offsets (double-buffered envs)
#define OFF_LL0 0
#define OFF_LL1 131072
#define OFF_LR0 262144
#define OFF_LR1 393216
#define OFF_NL0 524288
#define OFF_NL1 540672
#define OFF_NR0 557056
#define OFF_NR1 573440
#define OFF_MREV 589824                  // 20*32768
#define OFF_HREV 1245184                 // 20*256
#define OFF_PART 1250304                 // 128 energy partials
#define OFF_PARTN 1250432                // 128 norm partials

// init boundary envs + build reversed tensors for the right sweep:
// Mrev[k][p][i][a] = M[39-k][a][i][p];  Hrev[k][x][w][i][j] = H[39-k][w][x][i][j]
__global__ __launch_bounds__(256) void k_prep(const float* __restrict__ Min,
                                              const float* __restrict__ Hin,
                                              float* __restrict__ ws) {
    int gid = blockIdx.x * 256 + threadIdx.x;
    int gsz = gridDim.x * 256;
    for (int i = gid; i < LSZ; i += gsz) {
        ws[OFF_LL0 + i] = (i == 0) ? 1.f : 0.f;               // L_left[0,0,0]
        ws[OFF_LR0 + i] = (i == (W - 1) * D) ? 1.f : 0.f;     // L_right[0,W-1,0]
    }
    for (int i = gid; i < NSZ; i += gsz) {
        ws[OFF_NL0 + i] = (i == 0) ? 1.f : 0.f;
        ws[OFF_NR0 + i] = (i == 0) ? 1.f : 0.f;
    }
    for (int idx = gid; idx < HALF * MSZ; idx += gsz) {
        int k = idx >> 15;
        int r = idx & (MSZ - 1);
        int p = r >> 8, i = (r >> 7) & 1, a = r & 127;
        ws[OFF_MREV + idx] = Min[(NS - 1 - k) * MSZ + a * 256 + i * 128 + p];
    }
    for (int idx = gid; idx < HALF * HSZ; idx += gsz) {
        int k = idx >> 8, r = idx & 255;
        int x = r >> 5, w = (r >> 2) & 7, i = (r >> 1) & 1, j = r & 1;
        ws[OFF_HREV + idx] = Hin[(NS - 1 - k) * HSZ + w * 32 + x * 4 + i * 2 + j];
    }
}

// One fused site-step. Energy blocks 0..127 (64/side, p-slice of 2):
//   T1[w,b,i,p] = sum_a L[a,w,b] m[a,i,p]      (L read from L2, once/block)
//   T2[p,x,b,j] = sum_{w,i} T1 h               (in LDS)
//   L'[p,x,q]   = sum_{b,j} T2 m[b,j,q]        (write double-buffered L)
// Norm blocks 128..159 (16/side, p-slice of 8): same with h omitted.
__global__ __launch_bounds__(256) void k_step(const float* __restrict__ Min,
                                              const float* __restrict__ Hin,
                                              float* __restrict__ ws, int kk) {
    __shared__ float sm[10112];
    const int bid = blockIdx.x;
    const int t = threadIdx.x;
    const int rd = kk & 1;
    if (bid < 128) {
        const int side = bid >> 6;
        const int lid = bid & 63;
        const int p0 = lid * 2;
        const int baseL = side ? OFF_LR0 : OFF_LL0;
        const float* Lsrc = ws + baseL + rd * LSZ;
        float* Ldst = ws + baseL + (rd ^ 1) * LSZ;
        const float* m = side ? (ws + OFF_MREV + kk * MSZ) : (Min + kk * MSZ);
        const float* h = side ? (ws + OFF_HREV + kk * HSZ) : (Hin + kk * HSZ);
        float* hs = sm;          // [16wi][16xj]
        float* ms = sm + 256;    // [128a][i*2+pp]
        float* T1s = sm + 768;   // [(pp*16+w*2+i)][128b pad->132]
        float* T2s = sm + 4992;  // [(p*128+b)*20 + j*8 + x]
        hs[t] = h[((t >> 4) >> 1) * 32 + ((t & 15) >> 1) * 4 +
                  ((t >> 4) & 1) * 2 + (t & 1)];
        {
            int a = t >> 1, pp = t & 1;
            ms[a * 4 + pp]     = m[a * 256 + p0 + pp];        // i=0
            ms[a * 4 + 2 + pp] = m[a * 256 + 128 + p0 + pp];  // i=1
        }
        __syncthreads();
        // ---- phase 1: thread owns (w, 4 consecutive b), all 4 (i,p) ----
        {
            const int w = t >> 5, bq = t & 31;
            float acc[4][4]; // [bb][c=i*2+pp]
#pragma unroll
            for (int u = 0; u < 4; ++u)
#pragma unroll
                for (int v = 0; v < 4; ++v) acc[u][v] = 0.f;
            const float* Lp = Lsrc + w * 128 + bq * 4;
#pragma unroll 4
            for (int a = 0; a < 128; ++a) {
                const float4 lv = *(const float4*)&Lp[a * 1024];
                const float4 mv = *(const float4*)&ms[a * 4];
                acc[0][0] += lv.x * mv.x; acc[0][1] += lv.x * mv.y;
                acc[0][2] += lv.x * mv.z; acc[0][3] += lv.x * mv.w;
                acc[1][0] += lv.y * mv.x; acc[1][1] += lv.y * mv.y;
                acc[1][2] += lv.y * mv.z; acc[1][3] += lv.y * mv.w;
                acc[2][0] += lv.z * mv.x; acc[2][1] += lv.z * mv.y;
                acc[2][2] += lv.z * mv.z; acc[2][3] += lv.z * mv.w;
                acc[3][0] += lv.w * mv.x; acc[3][1] += lv.w * mv.y;
                acc[3][2] += lv.w * mv.z; acc[3][3] += lv.w * mv.w;
            }
#pragma unroll
            for (int c = 0; c < 4; ++c) {
                int i = c >> 1, pp = c & 1;
                float4 v;
                v.x = acc[0][c]; v.y = acc[1][c]; v.z = acc[2][c]; v.w = acc[3][c];
                *(float4*)&T1s[(pp * 16 + w * 2 + i) * 132 + bq * 4] = v;
            }
        }
        __syncthreads();
        // ---- phase 2: thread owns (b, p-local); contract h in registers ----
        {
            const int b = t & 127, p = t >> 7;
            float tv[16];
#pragma unroll
            for (int wi = 0; wi < 16; ++wi)
                tv[wi] = T1s[(p * 16 + wi) * 132 + b];
            float o[16];
#pragma unroll
            for (int xj = 0; xj < 16; ++xj) o[xj] = 0.f;
#pragma unroll
            for (int wi = 0; wi < 16; ++wi) {
                float tvv = tv[wi];
                float4 h0 = *(float4*)&hs[wi * 16];
                float4 h1 = *(float4*)&hs[wi * 16 + 4];
                float4 h2 = *(float4*)&hs[wi * 16 + 8];
                float4 h3 = *(float4*)&hs[wi * 16 + 12];
                o[0] += tvv * h0.x;  o[1] += tvv * h0.y;  o[2] += tvv * h0.z;  o[3] += tvv * h0.w;
                o[4] += tvv * h1.x;  o[5] += tvv * h1.y;  o[6] += tvv * h1.z;  o[7] += tvv * h1.w;
                o[8] += tvv * h2.x;  o[9] += tvv * h2.y;  o[10] += tvv * h2.z; o[11] += tvv * h2.w;
                o[12] += tvv * h3.x; o[13] += tvv * h3.y; o[14] += tvv * h3.z; o[15] += tvv * h3.w;
            }
            // o[xj] = T2[p][x=xj>>1][b][j=xj&1] -> T2s[(p*128+b)*20 + j*8 + x]
            const int base2 = (p * 128 + b) * 20;
            float4 v0; v0.x = o[0];  v0.y = o[2];  v0.z = o[4];  v0.w = o[6];
            float4 v1; v1.x = o[8];  v1.y = o[10]; v1.z = o[12]; v1.w = o[14];
            float4 v2; v2.x = o[1];  v2.y = o[3];  v2.z = o[5];  v2.w = o[7];
            float4 v3; v3.x = o[9];  v3.y = o[11]; v3.z = o[13]; v3.w = o[15];
            *(float4*)&T2s[base2]      = v0;
            *(float4*)&T2s[base2 + 4]  = v1;
            *(float4*)&T2s[base2 + 8]  = v2;
            *(float4*)&T2s[base2 + 12] = v3;
        }
        __syncthreads();
        // ---- phase 3: thread owns (q, p-local); K=(b,j)=256; m flat k2*128+q ----
        {
            const int q = t & 127, p = t >> 7;
            float o3[8];
#pragma unroll
            for (int x = 0; x < 8; ++x) o3[x] = 0.f;
            const float* mq = m + q;
            const float* T2p = T2s + p * 128 * 20;
#pragma unroll 4
            for (int k2 = 0; k2 < 256; ++k2) {
                float mv = mq[k2 * 128];
                const float* tp = &T2p[(k2 >> 1) * 20 + (k2 & 1) * 8];
                float4 ta = *(const float4*)tp;
                float4 tb = *(const float4*)(tp + 4);
                o3[0] += ta.x * mv; o3[1] += ta.y * mv;
                o3[2] += ta.z * mv; o3[3] += ta.w * mv;
                o3[4] += tb.x * mv; o3[5] += tb.y * mv;
                o3[6] += tb.z * mv; o3[7] += tb.w * mv;
            }
            float* Lo = Ldst + (p0 + p) * 1024 + q;
#pragma unroll
            for (int x = 0; x < 8; ++x) Lo[x * 128] = o3[x];
        }
    } else {
        // ---- norm block: p-slice of 8 ----
        const int nb = bid - 128;
        const int side = nb >> 4;
        const int nlid = nb & 15;
        const int p0 = nlid * 8;
        const int baseN = side ? OFF_NR0 : OFF_NL0;
        const float* Nsrc = ws + baseN + rd * NSZ;
        float* Ndst = ws + baseN + (rd ^ 1) * NSZ;
        const float* m = side ? (ws + OFF_MREV + kk * MSZ) : (Min + kk * MSZ);
        float* msn = sm;        // [128a][i*8+pp]
        float* Tns = sm + 2048; // [256 r=(b,i)][8 p]
#pragma unroll
        for (int u = 0; u < 8; ++u) {
            int e = u * 256 + t;
            int a = e >> 4, i = (e >> 3) & 1, pp = e & 7;
            msn[e] = m[a * 256 + i * 128 + p0 + pp];
        }
        __syncthreads();
        {
            const int b = t >> 1, i = t & 1;
            float acc1[8];
#pragma unroll
            for (int u = 0; u < 8; ++u) acc1[u] = 0.f;
            const float* Np = Nsrc + b;
            const float* mp = msn + i * 8;
#pragma unroll 2
            for (int a = 0; a < 128; ++a) {
                float nv = Np[a * 128];
                float4 m0 = *(const float4*)&mp[a * 16];
                float4 m1 = *(const float4*)&mp[a * 16 + 4];
                acc1[0] += nv * m0.x; acc1[1] += nv * m0.y;
                acc1[2] += nv * m0.z; acc1[3] += nv * m0.w;
                acc1[4] += nv * m1.x; acc1[5] += nv * m1.y;
                acc1[6] += nv * m1.z; acc1[7] += nv * m1.w;
            }
            float4 s0; s0.x = acc1[0]; s0.y = acc1[1]; s0.z = acc1[2]; s0.w = acc1[3];
            float4 s1; s1.x = acc1[4]; s1.y = acc1[5]; s1.z = acc1[6]; s1.w = acc1[7];
            *(float4*)&Tns[t * 8] = s0;
            *(float4*)&Tns[t * 8 + 4] = s1;
        }
        __syncthreads();
        {
            const int q = t & 127, ph = t >> 7;
            float a3[4] = {0.f, 0.f, 0.f, 0.f};
            const float* mq = m + q;
            const float* Tp = Tns + ph * 4;
#pragma unroll 4
            for (int k2 = 0; k2 < 256; ++k2) {
                float mv = mq[k2 * 128];
                float4 tv = *(const float4*)&Tp[k2 * 8];
                a3[0] += tv.x * mv; a3[1] += tv.y * mv;
                a3[2] += tv.z * mv; a3[3] += tv.w * mv;
            }
            float* No = Ndst + (p0 + ph * 4) * 128 + q;
#pragma unroll
            for (int pp = 0; pp < 4; ++pp) No[pp * 128] = a3[pp];
        }
    }
}

// Partial dots: 128 blocks; final envs are in buffer 0 after 20 steps.
__global__ __launch_bounds__(256) void k_dot(float* __restrict__ ws) {
    __shared__ float se[256], sn[256];
    int bid = blockIdx.x, t = threadIdx.x;
    const float* LL = ws + OFF_LL0;
    const float* LR = ws + OFF_LR0;
    float e = 0.f;
#pragma unroll
    for (int u = 0; u < 4; ++u) {
        int i = bid * 1024 + u * 256 + t;
        e += LL[i] * LR[i];
    }
    float n = 0.f;
    if (t < 128) {
        int i = bid * 128 + t;
        n = ws[OFF_NL0 + i] * ws[OFF_NR0 + i];
    }
    se[t] = e;
    sn[t] = n;
    __syncthreads();
    for (int s = 128; s > 0; s >>= 1) {
        if (t < s) { se[t] += se[t + s]; sn[t] += sn[t + s]; }
        __syncthreads();
    }
    if (t == 0) {
        ws[OFF_PART + bid] = se[0];
        ws[OFF_PARTN + bid] = sn[0];
    }
}

__global__ __launch_bounds__(256) void k_loss(const float* __restrict__ ws,
                                              float* __restrict__ out) {
    __shared__ float se[128], sn[128];
    int t = threadIdx.x;
    if (t < 128) {
        se[t] = ws[OFF_PART + t];
        sn[t] = ws[OFF_PARTN + t];
    }
    __syncthreads();
    for (int s = 64; s > 0; s >>= 1) {
        if (t < s) { se[t] += se[t + s]; sn[t] += sn[t + s]; }
        __syncthreads();
    }
    if (t == 0) {
        float E = se[0], Nm = sn[0];
        out[0] = E;
        out[1] = Nm;
        out[2] = E / Nm;
        out[3] = fmaxf(Nm - 10000.0f, 0.0f);
    }
}

extern "C" void kernel_launch(void* const* d_in, const int* in_sizes, int n_in,
                              void* d_out, int out_size, void* d_ws, size_t ws_size,
                              hipStream_t stream) {
    const float* Min = (const float*)d_in[0];
    const float* Hin = (const float*)d_in[1];
    float* ws = (float*)d_ws;
    float* out = (float*)d_out;
    (void)in_sizes; (void)n_in; (void)out_size; (void)ws_size;

    k_prep<<<dim3(512), dim3(256), 0, stream>>>(Min, Hin, ws);
    for (int k = 0; k < HALF; ++k) {
        k_step<<<dim3(160), dim3(256), 0, stream>>>(Min, Hin, ws, k);
    }
    k_dot<<<dim3(128), dim3(256), 0, stream>>>(ws);
    k_loss<<<dim3(1), dim3(256), 0, stream>>>(ws, out);
}